// Round 9
// baseline (229.412 us; speedup 1.0000x reference)
//
#include <hip/hip_runtime.h>
#include <math.h>

// Problem constants (B=4, S=2048, H=1024, E=16, TOP_K=4)
constexpr int kTokens = 8192;   // B*S
constexpr int kH      = 1024;
constexpr int kE      = 16;
constexpr int kTopK   = 4;

// ---------------------------------------------------------------------------
// Stage 1 v9: PURE VMEM+VALU loop. No LDS, no SMEM, no barriers -- all waits
// are fine-grained vmcnt, the one regime the compiler schedules near-
// optimally (8 rounds of LDS/SMEM variants all pinned at <=19% VALUBusy by
// lgkmcnt cross-pipe drains / barrier stalls).
// Lane (tq = ln>>2, eq = ln&3) owns tokens {tq+16i} and the h-subset
// {h : (h>>2) mod 4 == eq}; it accumulates facc[4 tok][16 e] over its h.
//  - x load x[tok][h0+q*16+eq*4 ..+4]: 4 eq x 16 tq lanes = 16 full 64-B
//    lines per instr, perfectly coalesced, straight to VGPRs.
//  - W load W[h][0..16): per instr 4 distinct 64-B rows (16-way broadcast),
//    L1/L2-resident (256 KB total weights).
//  - epilogue: 2-round __shfl_xor (xor 1, xor 2) sums the 4 eq-lanes; lane
//    stores its own e-quad -> coalesced 1 KB float4 stores. ~300 instrs, once.
// Block = 1 wave = 64 tokens x one 128-k slice. Grid = NC(=32) slices x 128
// token groups = 4096 waves (4/SIMD at VGPR<=128 via __launch_bounds__).
// Numerics: fp32 accum over 128-k slice + pairwise lane sums (err ~3e-7);
// stage 2 folds the 32 slices + biases in fp64 -- same scheme all 8 passing
// rounds (absmax 9.8e-4 vs threshold 0.3).
// ---------------------------------------------------------------------------
template<int NC>
__global__ __launch_bounds__(64, 4)
void router_fmac(const float* __restrict__ x,   const float* __restrict__ img,
                 const float* __restrict__ txt, const float* __restrict__ aud,
                 const float* __restrict__ Wg,  const float* __restrict__ Wi,
                 const float* __restrict__ Wt,  const float* __restrict__ Wa,
                 float* __restrict__ partials)
{
    constexpr int KEXT = 4096 / NC;   // k-cols per slice (128 @ NC=32)
    constexpr int NQ   = KEXT / 16;   // 16-h quad-groups per slice (8)
    constexpr int MS   = NC / 4;      // slices per modality (8)

    const int ln = threadIdx.x;
    const int tq = ln >> 2;           // token slot 0..15
    const int eq = ln & 3;            // e-quad / h-phase 0..3
    const int ks = blockIdx.x >> 7;   // k-slice (slow digit)
    const int tg = blockIdx.x & 127;  // token group
    const int m  = ks / MS;           // modality
    const int h0 = (ks % MS) * KEXT;  // h offset within modality
    const int tok0 = tg * 64;

    const float* Xm = (m == 0) ? x  : (m == 1) ? img : (m == 2) ? txt : aud;
    const float* Wm = (m == 0) ? Wg : (m == 1) ? Wi  : (m == 2) ? Wt  : Wa;

    float facc[4][kE];
#pragma unroll
    for (int i = 0; i < 4; ++i)
#pragma unroll
        for (int e = 0; e < kE; ++e) facc[i][e] = 0.f;

    const float* xp[4];
#pragma unroll
    for (int i = 0; i < 4; ++i)
        xp[i] = Xm + (size_t)(tok0 + tq + 16 * i) * kH + h0 + eq * 4;
    const float* wp = Wm + (size_t)(h0 + eq * 4) * kE;   // row h0+eq*4

#pragma unroll 2
    for (int q = 0; q < NQ; ++q) {
        // this lane's 4 h-values this group: h = h0 + q*16 + eq*4 + j
        float4 xv[4];
#pragma unroll
        for (int i = 0; i < 4; ++i)
            xv[i] = *(const float4*)(xp[i] + q * 16);

#pragma unroll
        for (int j = 0; j < 4; ++j) {
            const float* wr = wp + (size_t)(q * 16 + j) * kE;   // W[h][0..16)
            const float4 w0 = ((const float4*)wr)[0];
            const float4 w1 = ((const float4*)wr)[1];
            const float4 w2 = ((const float4*)wr)[2];
            const float4 w3 = ((const float4*)wr)[3];
#pragma unroll
            for (int i = 0; i < 4; ++i) {
                const float xh = (j == 0) ? xv[i].x : (j == 1) ? xv[i].y
                               : (j == 2) ? xv[i].z : xv[i].w;
                facc[i][0]  += xh * w0.x;  facc[i][1]  += xh * w0.y;
                facc[i][2]  += xh * w0.z;  facc[i][3]  += xh * w0.w;
                facc[i][4]  += xh * w1.x;  facc[i][5]  += xh * w1.y;
                facc[i][6]  += xh * w1.z;  facc[i][7]  += xh * w1.w;
                facc[i][8]  += xh * w2.x;  facc[i][9]  += xh * w2.y;
                facc[i][10] += xh * w2.z;  facc[i][11] += xh * w2.w;
                facc[i][12] += xh * w3.x;  facc[i][13] += xh * w3.y;
                facc[i][14] += xh * w3.z;  facc[i][15] += xh * w3.w;
            }
        }
    }

    // ---- butterfly-sum the 4 h-phase lanes (xor 1, xor 2) ----
#pragma unroll
    for (int i = 0; i < 4; ++i)
#pragma unroll
        for (int e = 0; e < kE; ++e) {
            float v = facc[i][e];
            v += __shfl_xor(v, 1, 64);
            v += __shfl_xor(v, 2, 64);
            facc[i][e] = v;
        }

    // ---- store: lane writes its own e-quad for its 4 tokens (static idx
    // via eq-predication; 4 eq x 16 tq lanes = 1 KB contiguous per instr) ----
#pragma unroll
    for (int i = 0; i < 4; ++i) {
        float o0, o1, o2, o3;
        if (eq == 0)      { o0 = facc[i][0];  o1 = facc[i][1];  o2 = facc[i][2];  o3 = facc[i][3];  }
        else if (eq == 1) { o0 = facc[i][4];  o1 = facc[i][5];  o2 = facc[i][6];  o3 = facc[i][7];  }
        else if (eq == 2) { o0 = facc[i][8];  o1 = facc[i][9];  o2 = facc[i][10]; o3 = facc[i][11]; }
        else              { o0 = facc[i][12]; o1 = facc[i][13]; o2 = facc[i][14]; o3 = facc[i][15]; }
        const int token = tok0 + tq + 16 * i;
        *(float4*)&partials[((size_t)ks * kTokens + token) * kE + eq * 4] =
            make_float4(o0, o1, o2, o3);
    }
}

// ---------------------------------------------------------------------------
// Stage 2: combine NC slice-partials + biases (fp64), softmax, top-k, output
// writes, per-block expert sums. Block = 64 tokens x 256 threads.
// ---------------------------------------------------------------------------
template<int NC>
__global__ __launch_bounds__(256)
void router_topk(const float* __restrict__ partials,
                 const float* __restrict__ bg, const float* __restrict__ bi,
                 const float* __restrict__ bt, const float* __restrict__ ba,
                 float* __restrict__ out, float* __restrict__ blocksum)
{
    __shared__ double lgs[64][kE + 1];
    __shared__ float  pr[64][kE + 1];

    const int t    = threadIdx.x;
    const int tq   = t >> 2;      // token offset 0..63
    const int eq   = t & 3;       // e-quad
    const int tok0 = blockIdx.x * 64;

    double a0 = (double)bg[eq*4+0] + (double)bi[eq*4+0] + (double)bt[eq*4+0] + (double)ba[eq*4+0];
    double a1 = (double)bg[eq*4+1] + (double)bi[eq*4+1] + (double)bt[eq*4+1] + (double)ba[eq*4+1];
    double a2 = (double)bg[eq*4+2] + (double)bi[eq*4+2] + (double)bt[eq*4+2] + (double)ba[eq*4+2];
    double a3 = (double)bg[eq*4+3] + (double)bi[eq*4+3] + (double)bt[eq*4+3] + (double)ba[eq*4+3];

#pragma unroll
    for (int c = 0; c < NC; ++c) {
        const float4 v = *(const float4*)(partials + ((size_t)c * kTokens + tok0 + tq) * kE + eq * 4);
        a0 += (double)v.x;  a1 += (double)v.y;  a2 += (double)v.z;  a3 += (double)v.w;
    }
    lgs[tq][eq*4+0] = a0;  lgs[tq][eq*4+1] = a1;
    lgs[tq][eq*4+2] = a2;  lgs[tq][eq*4+3] = a3;
    __syncthreads();

    if (t < 64) {
        const int tok = tok0 + t;
        double lg[kE];
#pragma unroll
        for (int e = 0; e < kE; ++e) lg[e] = lgs[t][e];

        double mx = lg[0];
#pragma unroll
        for (int e = 1; e < kE; ++e) mx = fmax(mx, lg[e]);

        float p[kE];
        float sum = 0.f;
#pragma unroll
        for (int e = 0; e < kE; ++e) {
            p[e] = expf((float)(lg[e] - mx));
            sum += p[e];
        }
        const float inv = 1.f / sum;
#pragma unroll
        for (int e = 0; e < kE; ++e) { p[e] *= inv; pr[t][e] = p[e]; }

        // top-4, descending, ties -> smallest index (matches jax.lax.top_k)
        unsigned used = 0;
        float tp[kTopK];
        int   ti[kTopK];
        float s4 = 0.f;
#pragma unroll
        for (int k = 0; k < kTopK; ++k) {
            float best = -1.f;
            int   bidx = 0;
#pragma unroll
            for (int e = 0; e < kE; ++e) {
                if (!((used >> e) & 1u) && p[e] > best) { best = p[e]; bidx = e; }
            }
            used |= 1u << bidx;
            tp[k] = best;
            ti[k] = bidx;
            s4 += best;
        }
        const float rn = 1.f / s4;

        *(float4*)&out[(size_t)tok * kTopK] =
            make_float4((float)ti[0], (float)ti[1], (float)ti[2], (float)ti[3]);
        *(float4*)&out[(size_t)kTokens * kTopK + (size_t)tok * kTopK] =
            make_float4(tp[0] * rn, tp[1] * rn, tp[2] * rn, tp[3] * rn);
    }
    __syncthreads();

    if (t < kE) {
        float s = 0.f;
#pragma unroll
        for (int tk = 0; tk < 64; ++tk) s += pr[tk][t];
        blocksum[blockIdx.x * kE + t] = s;
    }
}

// ---------------------------------------------------------------------------
// Stage 3: 128 block-partials -> mean prob per expert -> aux loss scalar
// ---------------------------------------------------------------------------
__global__ __launch_bounds__(64)
void router_aux(const float* __restrict__ blocksum, float* __restrict__ out)
{
    __shared__ double ps[kE];
    const int t = threadIdx.x;
    if (t < kE) {
        double s = 0.0;
        for (int b = 0; b < 128; ++b) s += (double)blocksum[b * kE + t];
        ps[t] = s / (double)kTokens;
    }
    __syncthreads();
    if (t == 0) {
        double aux = 0.0;
#pragma unroll
        for (int e = 0; e < kE; ++e) aux += ps[e] * log(ps[e] * (double)kE + 1e-9);
        out[(size_t)kTokens * kTopK * 2] = (float)aux;  // element 65536
    }
}

extern "C" void kernel_launch(void* const* d_in, const int* in_sizes, int n_in,
                              void* d_out, int out_size, void* d_ws, size_t ws_size,
                              hipStream_t stream)
{
    const float* x   = (const float*)d_in[0];
    const float* img = (const float*)d_in[1];
    const float* txt = (const float*)d_in[2];
    const float* aud = (const float*)d_in[3];
    const float* Wg  = (const float*)d_in[4];
    const float* bg  = (const float*)d_in[5];
    const float* Wi  = (const float*)d_in[6];
    const float* bi  = (const float*)d_in[7];
    const float* Wt  = (const float*)d_in[8];
    const float* bt  = (const float*)d_in[9];
    const float* Wa  = (const float*)d_in[10];
    const float* ba  = (const float*)d_in[11];

    float* out = (float*)d_out;

    const size_t need32 = (size_t)32 * kTokens * kE * 4 + 128 * kE * 4;  // 16.8 MB
    if (ws_size >= need32) {   // proven to fit (R8 ran this branch)
        float* partials = (float*)d_ws;
        float* blocksum = (float*)((char*)d_ws + (size_t)32 * kTokens * kE * 4);
        router_fmac<32><<<32 * 128, 64, 0, stream>>>(x, img, txt, aud, Wg, Wi, Wt, Wa, partials);
        router_topk<32><<<128, 256, 0, stream>>>(partials, bg, bi, bt, ba, out, blocksum);
        router_aux<<<1, 64, 0, stream>>>(blocksum, out);
    } else {
        float* partials = (float*)d_ws;                                  // 8.4 MB fallback
        float* blocksum = (float*)((char*)d_ws + (size_t)16 * kTokens * kE * 4);
        router_fmac<16><<<16 * 128, 64, 0, stream>>>(x, img, txt, aud, Wg, Wi, Wt, Wa, partials);
        router_topk<16><<<128, 256, 0, stream>>>(partials, bg, bi, bt, ba, out, blocksum);
        router_aux<<<1, 64, 0, stream>>>(blocksum, out);
    }
}